// Round 4
// baseline (72.820 us; speedup 1.0000x reference)
//
#include <hip/hip_runtime.h>

// NBCModel: non-backtracking closed-walk signature + MLP.
// B[i,j] = (dst_j == src_i) && (src_j != dst_i).  sig[g,k] = sum over edges i
// in graph g of diag(B^{k+1})_i.  out[g] = relu(sig @ W1 + b1) @ W2 + b2.
//
// History: R1 DFS 151; R2 BFS 90.5; R3 ballot neutral; R4 81.4; R5 3-kernel
// 82.1; R6 single-kernel chain-build, 1024thr 73.75; R7 32-block device-sync
// 87.1; R8 512thr 76.5; R9 73.75 (= R6); R10 wave-private frontiers 70.63;
// R11 plain-atomicAdd push + empty-level break 69.85 (BEST).
// R12: critical-path latency cuts.
//  (a) prefetch cur[lane], cur[lane+64] BEFORE the level fence (same-wave DS
//      in-order => read-after-own-write is safe; fence's lgkmcnt covers both)
//      so the frontier read overlaps the nn[d] counter read.
//  (b) level body = 2-way interleaved chain walk over the two slots (L0
//      style): waves with >64 level-1 entries no longer run a 2nd serial
//      pass — their chain latency is hidden, and they gate B4.
//  (c) MLP tail: 8 partial sums live in 8 contiguous lanes of one wave ->
//      width-8 __shfl_down reduction; s_part round-trip and B5 deleted
//      (block barriers 5 -> 4).
//  (d) head poison init via 2x ds_write_b64 instead of 4x ds_write_b32.

typedef unsigned long long u64;

constexpr int E_EDGES  = 2048;
constexpr int L_WALK   = 8;
constexpr int G_GRAPHS = 128;
constexpr int HID      = 128;
constexpr int TPB      = 1024;
constexpr int NWAVE    = TPB / 64;   // 16 waves
constexpr int CAPW     = 128;        // per-wave frontier capacity (exp ~64 @L1)
constexpr int NIL      = 0xFFF;

__device__ __forceinline__ void push(u64 e2, int* ctr, u64* buf) {
    int p = atomicAdd(ctr, 1);       // wave-local counter: intra-wave contention only
    if (p < CAPW) buf[p] = e2;
}

__launch_bounds__(TPB, 1)
__global__ void nbc_all(const int* __restrict__ edge_index,
                        const int* __restrict__ edge_graph,
                        const float* __restrict__ W1,
                        const float* __restrict__ b1,
                        const float* __restrict__ W2,
                        const float* __restrict__ b2,
                        float* __restrict__ out)
{
    // node entry q: src(0:12) | dst(12:24) | hs=head[src](24:36) | next(36:48)
    // frontier  e: s(0:11) | dst_cur(11:23) | ptr(23:35) | g(35:42)
    __shared__ u64 s_buf[NWAVE * 2 * CAPW];  // 32 KB; first 16 KB alias head[4096]
    __shared__ u64 s_node[E_EDGES];          // 16 KB
    __shared__ int s_sig[G_GRAPHS * L_WALK]; // 4 KB
    __shared__ int s_nn[NWAVE * 12];         // per-wave level counters (0.75 KB)
    __shared__ float s_W1[L_WALK * HID];     // 4 KB
    __shared__ float s_b1[HID];
    __shared__ float s_W2[HID];
    __shared__ float s_b2;
    // total ~58 KB static LDS (<= 64 KB limit)

    int* s_head = (int*)s_buf;               // 4096 ints == first 2048 u64, dead after B3

    const int t    = threadIdx.x;
    const int lane = t & 63;
    const int wid  = t >> 6;

    // ---- phase 1: issue all global loads early; init LDS ----
    const int2 se2 = ((const int2*)edge_index)[t];              // src of 2t,2t+1
    const int2 de2 = ((const int2*)(edge_index + E_EDGES))[t];  // dst
    const int2 ge2 = ((const int2*)edge_graph)[t];              // graph ids
    s_W1[t] = W1[t];                         // L_WALK*HID == 1024
    if (t < HID) { s_b1[t] = b1[t]; s_W2[t] = W2[t]; }
    if (t == 0) s_b2 = b2[0];
    s_sig[t] = 0;                            // G*L == 1024
    if (t < NWAVE * 12) s_nn[t] = 0;
    s_buf[t]       = ~0ull;                  // head[4096] = -1 via 2x ds_write_b64
    s_buf[t + TPB] = ~0ull;
    __syncthreads();                                            // B1

    // ---- phase 2: chain build: head[x] = list of edges b with dst_b == x ----
    const int e0 = 2 * t, e1 = 2 * t + 1;
    const int prev0 = atomicExch(&s_head[de2.x], e0);
    const int prev1 = atomicExch(&s_head[de2.y], e1);
    __syncthreads();                                            // B2

    // ---- phase 3: read hs = head[src_e]; single full node write ----
    const int h0 = s_head[se2.x] & NIL;
    const int h1 = s_head[se2.y] & NIL;
    s_node[e0] = (u64)se2.x | ((u64)de2.x << 12) | ((u64)h0 << 24)
               | ((u64)(prev0 & NIL) << 36);
    s_node[e1] = (u64)se2.y | ((u64)de2.y << 12) | ((u64)h1 << 24)
               | ((u64)(prev1 & NIL) << 36);
    __syncthreads();                                            // B3 (s_node built; heads dead)

    // ---- wave-private frontier setup ----
    int* nn   = s_nn + wid * 12;
    u64* bufA = s_buf + (size_t)(wid * 2) * CAPW;
    u64* bufB = bufA + CAPW;

    // ---- level 0 from registers: 2-way interleaved chain chase ----
    // (edges e0=2t, e1=2t+1 both belong to wave wid = t>>6)
    {
        int p0 = h0, p1 = h1;
        while ((p0 != NIL) | (p1 != NIL)) {
            u64 q0 = (p0 != NIL) ? s_node[p0] : 0;   // independent ds_reads
            u64 q1 = (p1 != NIL) ? s_node[p1] : 0;
            if (p0 != NIL) {
                int sb = (int)(q0 & NIL);
                if (sb != de2.x) {                    // non-backtracking
                    if (p0 == e0) atomicAdd(&s_sig[ge2.x * L_WALK + 0], 1);
                    u64 en = (u64)e0 | (((q0 >> 12) & 0xFFFFFFull) << 11)
                           | ((u64)ge2.x << 35);
                    push(en, &nn[1], bufA);
                }
                p0 = (int)((q0 >> 36) & NIL);
            }
            if (p1 != NIL) {
                int sb = (int)(q1 & NIL);
                if (sb != de2.y) {
                    if (p1 == e1) atomicAdd(&s_sig[ge2.y * L_WALK + 0], 1);
                    u64 en = (u64)e1 | (((q1 >> 12) & 0xFFFFFFull) << 11)
                           | ((u64)ge2.y << 35);
                    push(en, &nn[1], bufA);
                }
                p1 = (int)((q1 >> 36) & NIL);
            }
        }
    }
    // NO block barrier: each wave proceeds independently from here.

    // ---- levels 1..7: wave-private, fence-only ordering, 2-slot interleave ----
    u64* cur = bufA;
    u64* nxt = bufB;
    for (int d = 1; d < L_WALK; ++d) {
        // Prefetch both frontier slots BEFORE the fence: same-wave DS ops are
        // in-order, so read-after-own-write returns the pushed values; the
        // fence's lgkmcnt(0) waits for these reads too.
        u64 eA = cur[lane];
        u64 eB = cur[lane + 64];
        __threadfence_block();
        int n_cur = nn[d];
        if (n_cur == 0) break;   // wave-private: empty level => all deeper empty
        if (n_cur > CAPW) n_cur = CAPW;

        int sA = 0, dccA = 0, ptrA = NIL; u64 gbA = 0;
        int sB = 0, dccB = 0, ptrB = NIL; u64 gbB = 0;
        if (lane < n_cur) {
            sA   = (int)( eA        & 0x7FF);
            dccA = (int)((eA >> 11) & NIL);
            ptrA = (int)((eA >> 23) & NIL);
            gbA  = eA & (0x7Full << 35);
        }
        if (lane + 64 < n_cur) {
            sB   = (int)( eB        & 0x7FF);
            dccB = (int)((eB >> 11) & NIL);
            ptrB = (int)((eB >> 23) & NIL);
            gbB  = eB & (0x7Full << 35);
        }
        while ((ptrA != NIL) | (ptrB != NIL)) {
            u64 qA = (ptrA != NIL) ? s_node[ptrA] : 0;  // independent ds_reads
            u64 qB = (ptrB != NIL) ? s_node[ptrB] : 0;
            if (ptrA != NIL) {
                int sb = (int)(qA & NIL);
                if (sb != dccA) {
                    if (ptrA == sA)
                        atomicAdd(&s_sig[(int)(gbA >> 35) * L_WALK + d], 1);
                    if (d < L_WALK - 1) {
                        u64 e2 = (u64)sA | (((qA >> 12) & 0xFFFFFFull) << 11) | gbA;
                        push(e2, &nn[d + 1], nxt);
                    }
                }
                ptrA = (int)((qA >> 36) & NIL);
            }
            if (ptrB != NIL) {
                int sb = (int)(qB & NIL);
                if (sb != dccB) {
                    if (ptrB == sB)
                        atomicAdd(&s_sig[(int)(gbB >> 35) * L_WALK + d], 1);
                    if (d < L_WALK - 1) {
                        u64 e2 = (u64)sB | (((qB >> 12) & 0xFFFFFFull) << 11) | gbB;
                        push(e2, &nn[d + 1], nxt);
                    }
                }
                ptrB = (int)((qB >> 36) & NIL);
            }
        }
        u64* tmp = cur; cur = nxt; nxt = tmp;
    }
    __syncthreads();                                            // B4 (all sigs in)

    // ---- MLP: per-8-lane shfl reduction (no barrier, no LDS round-trip) ----
    {
        const int g   = t >> 3;
        const int sub = t & 7;
        float sv[L_WALK];
        #pragma unroll
        for (int k = 0; k < L_WALK; ++k) sv[k] = (float)s_sig[g * L_WALK + k];
        float o = 0.0f;
        const int j0 = sub * 16;
        #pragma unroll 4
        for (int jj = 0; jj < 16; ++jj) {
            int j = j0 + jj;
            float a = s_b1[j];
            #pragma unroll
            for (int k = 0; k < L_WALK; ++k) a += sv[k] * s_W1[k * HID + j];
            o += fmaxf(a, 0.0f) * s_W2[j];
        }
        // 8 partials live in 8 contiguous lanes of one wave
        o += __shfl_down(o, 4, 8);
        o += __shfl_down(o, 2, 8);
        o += __shfl_down(o, 1, 8);
        if (sub == 0) out[g] = o + s_b2;
    }
}

extern "C" void kernel_launch(void* const* d_in, const int* in_sizes, int n_in,
                              void* d_out, int out_size, void* d_ws, size_t ws_size,
                              hipStream_t stream) {
    const int*   edge_index = (const int*)d_in[0];
    const int*   edge_graph = (const int*)d_in[1];
    const float* W1 = (const float*)d_in[2];
    const float* b1 = (const float*)d_in[3];
    const float* W2 = (const float*)d_in[4];
    const float* b2 = (const float*)d_in[5];
    float* out = (float*)d_out;

    nbc_all<<<1, TPB, 0, stream>>>(edge_index, edge_graph, W1, b1, W2, b2, out);
}

// Round 5
// 69.114 us; speedup vs baseline: 1.0536x; 1.0536x over previous
//
#include <hip/hip_runtime.h>

// NBCModel: non-backtracking closed-walk signature + MLP.
// B[i,j] = (dst_j == src_i) && (src_j != dst_i).  sig[g,k] = sum over edges i
// in graph g of diag(B^{k+1})_i.  out[g] = relu(sig @ W1 + b1) @ W2 + b2.
//
// History: R1 DFS 151; R2 BFS 90.5; R3 ballot neutral; R4 81.4; R5 3-kernel
// 82.1; R6 single-kernel chain-build, 1024thr 73.75; R7 32-block device-sync
// 87.1; R8 512thr 76.5; R9 73.75 (= R6); R10 wave-private frontiers 70.63;
// R11 plain-atomicAdd push + empty-level break 69.85 (BEST);
// R12 prefetch+2-slot-interleave 72.82 REGRESSION (loaded container AND the
// unconditional pre-fence prefetch added lgkmcnt latency to every level,
// incl. the terminating empty one; 2-slot body doubled predication state).
// R13: revert level loop to R11 exactly; keep only R12's two separable,
// strictly-less-work wins: (c) MLP tail via width-8 __shfl_down (deletes
// s_part LDS round-trip + barrier B5; block barriers 5 -> 4) and
// (d) head-poison init as 2x ds_write_b64 instead of 4x ds_write_b32.

typedef unsigned long long u64;

constexpr int E_EDGES  = 2048;
constexpr int L_WALK   = 8;
constexpr int G_GRAPHS = 128;
constexpr int HID      = 128;
constexpr int TPB      = 1024;
constexpr int NWAVE    = TPB / 64;   // 16 waves
constexpr int CAPW     = 128;        // per-wave frontier capacity (exp ~64 @L1)
constexpr int NIL      = 0xFFF;

__device__ __forceinline__ void push(u64 e2, int* ctr, u64* buf) {
    int p = atomicAdd(ctr, 1);       // wave-local counter: intra-wave contention only
    if (p < CAPW) buf[p] = e2;
}

__launch_bounds__(TPB, 1)
__global__ void nbc_all(const int* __restrict__ edge_index,
                        const int* __restrict__ edge_graph,
                        const float* __restrict__ W1,
                        const float* __restrict__ b1,
                        const float* __restrict__ W2,
                        const float* __restrict__ b2,
                        float* __restrict__ out)
{
    // node entry q: src(0:12) | dst(12:24) | hs=head[src](24:36) | next(36:48)
    // frontier  e: s(0:11) | dst_cur(11:23) | ptr(23:35) | g(35:42)
    __shared__ u64 s_buf[NWAVE * 2 * CAPW];  // 32 KB; first 16 KB alias head[4096]
    __shared__ u64 s_node[E_EDGES];          // 16 KB
    __shared__ int s_sig[G_GRAPHS * L_WALK]; // 4 KB
    __shared__ int s_nn[NWAVE * 12];         // per-wave level counters (0.75 KB)
    __shared__ float s_W1[L_WALK * HID];     // 4 KB
    __shared__ float s_b1[HID];
    __shared__ float s_W2[HID];
    __shared__ float s_b2;
    // total ~58 KB static LDS (<= 64 KB limit)

    int* s_head = (int*)s_buf;               // 4096 ints == first 2048 u64, dead after B3

    const int t    = threadIdx.x;
    const int wid  = t >> 6;

    // ---- phase 1: issue all global loads early; init LDS ----
    const int2 se2 = ((const int2*)edge_index)[t];              // src of 2t,2t+1
    const int2 de2 = ((const int2*)(edge_index + E_EDGES))[t];  // dst
    const int2 ge2 = ((const int2*)edge_graph)[t];              // graph ids
    s_W1[t] = W1[t];                         // L_WALK*HID == 1024
    if (t < HID) { s_b1[t] = b1[t]; s_W2[t] = W2[t]; }
    if (t == 0) s_b2 = b2[0];
    s_sig[t] = 0;                            // G*L == 1024
    if (t < NWAVE * 12) s_nn[t] = 0;
    s_buf[t]       = ~0ull;                  // head[4096] = -1 via 2x ds_write_b64
    s_buf[t + TPB] = ~0ull;
    __syncthreads();                                            // B1

    // ---- phase 2: chain build: head[x] = list of edges b with dst_b == x ----
    const int e0 = 2 * t, e1 = 2 * t + 1;
    const int prev0 = atomicExch(&s_head[de2.x], e0);
    const int prev1 = atomicExch(&s_head[de2.y], e1);
    __syncthreads();                                            // B2

    // ---- phase 3: read hs = head[src_e]; single full node write ----
    const int h0 = s_head[se2.x] & NIL;
    const int h1 = s_head[se2.y] & NIL;
    s_node[e0] = (u64)se2.x | ((u64)de2.x << 12) | ((u64)h0 << 24)
               | ((u64)(prev0 & NIL) << 36);
    s_node[e1] = (u64)se2.y | ((u64)de2.y << 12) | ((u64)h1 << 24)
               | ((u64)(prev1 & NIL) << 36);
    __syncthreads();                                            // B3 (s_node built; heads dead)

    // ---- wave-private frontier setup ----
    int* nn   = s_nn + wid * 12;
    u64* bufA = s_buf + (size_t)(wid * 2) * CAPW;
    u64* bufB = bufA + CAPW;

    // ---- level 0 from registers: 2-way interleaved chain chase ----
    // (edges e0=2t, e1=2t+1 both belong to wave wid = t>>6)
    {
        int p0 = h0, p1 = h1;
        while ((p0 != NIL) | (p1 != NIL)) {
            u64 q0 = (p0 != NIL) ? s_node[p0] : 0;   // independent ds_reads
            u64 q1 = (p1 != NIL) ? s_node[p1] : 0;
            if (p0 != NIL) {
                int sb = (int)(q0 & NIL);
                if (sb != de2.x) {                    // non-backtracking
                    if (p0 == e0) atomicAdd(&s_sig[ge2.x * L_WALK + 0], 1);
                    u64 en = (u64)e0 | (((q0 >> 12) & 0xFFFFFFull) << 11)
                           | ((u64)ge2.x << 35);
                    push(en, &nn[1], bufA);
                }
                p0 = (int)((q0 >> 36) & NIL);
            }
            if (p1 != NIL) {
                int sb = (int)(q1 & NIL);
                if (sb != de2.y) {
                    if (p1 == e1) atomicAdd(&s_sig[ge2.y * L_WALK + 0], 1);
                    u64 en = (u64)e1 | (((q1 >> 12) & 0xFFFFFFull) << 11)
                           | ((u64)ge2.y << 35);
                    push(en, &nn[1], bufA);
                }
                p1 = (int)((q1 >> 36) & NIL);
            }
        }
    }
    // NO block barrier: each wave proceeds independently from here.

    // ---- levels 1..7: wave-private, fence-only ordering (R11 structure) ----
    u64* cur = bufA;
    u64* nxt = bufB;
    for (int d = 1; d < L_WALK; ++d) {
        __threadfence_block();   // order this wave's pushes before its reads
        int n_cur = nn[d];
        if (n_cur == 0) break;   // wave-private: empty level => all deeper empty
        if (n_cur > CAPW) n_cur = CAPW;
        for (int idx = t & 63; idx < n_cur; idx += 64) {
            u64 e = cur[idx];
            int s   = (int)( e        & 0x7FF);
            int dcc = (int)((e >> 11) & NIL);
            int ptr = (int)((e >> 23) & NIL);
            u64 gb  = e & (0x7Full << 35);
            while (ptr != NIL) {
                u64 q = s_node[ptr];
                int sb = (int)(q & NIL);
                int nx = (int)((q >> 36) & NIL);
                if (sb != dcc) {
                    if (ptr == s)
                        atomicAdd(&s_sig[(int)(gb >> 35) * L_WALK + d], 1);
                    if (d < L_WALK - 1) {
                        u64 e2 = (u64)s | (((q >> 12) & 0xFFFFFFull) << 11) | gb;
                        push(e2, &nn[d + 1], nxt);
                    }
                }
                ptr = nx;
            }
        }
        u64* tmp = cur; cur = nxt; nxt = tmp;
    }
    __syncthreads();                                            // B4 (all sigs in)

    // ---- MLP: per-8-lane shfl reduction (no barrier, no LDS round-trip) ----
    {
        const int g   = t >> 3;
        const int sub = t & 7;
        float sv[L_WALK];
        #pragma unroll
        for (int k = 0; k < L_WALK; ++k) sv[k] = (float)s_sig[g * L_WALK + k];
        float o = 0.0f;
        const int j0 = sub * 16;
        #pragma unroll 4
        for (int jj = 0; jj < 16; ++jj) {
            int j = j0 + jj;
            float a = s_b1[j];
            #pragma unroll
            for (int k = 0; k < L_WALK; ++k) a += sv[k] * s_W1[k * HID + j];
            o += fmaxf(a, 0.0f) * s_W2[j];
        }
        // 8 partials live in 8 contiguous lanes of one wave
        o += __shfl_down(o, 4, 8);
        o += __shfl_down(o, 2, 8);
        o += __shfl_down(o, 1, 8);
        if (sub == 0) out[g] = o + s_b2;
    }
}

extern "C" void kernel_launch(void* const* d_in, const int* in_sizes, int n_in,
                              void* d_out, int out_size, void* d_ws, size_t ws_size,
                              hipStream_t stream) {
    const int*   edge_index = (const int*)d_in[0];
    const int*   edge_graph = (const int*)d_in[1];
    const float* W1 = (const float*)d_in[2];
    const float* b1 = (const float*)d_in[3];
    const float* W2 = (const float*)d_in[4];
    const float* b2 = (const float*)d_in[5];
    float* out = (float*)d_out;

    nbc_all<<<1, TPB, 0, stream>>>(edge_index, edge_graph, W1, b1, W2, b2, out);
}